// Round 16
// baseline (8354.488 us; speedup 1.0000x reference)
//
#include <hip/hip_runtime.h>
#include <hip/hip_bf16.h>
#include <math.h>

#define Bn 512
#define Tn 256
#define Hn 512
#define Vn 7
#define BH (Bn*Hn)          // 262144
#define NLP (Bn*Tn*Vn)      // 917504
#define WSZ (4*Hn*Hn)       // 1048576 W elements

#define NBLK 256            // 1 block/CU
#define NTHR 512
#define NGRP 16             // groups of 32 batch rows
#define GBLK 16             // blocks per group (j-tiles of width 32)
#define CNT_STRIDE 32

#define RST 132             // red row stride: 128 jg + 4 pad
#define REDH (32*RST)       // one K-half slab

// Round-24: pre-split everything. R15 passed (absmax 0.0, 5579us) confirming
// the latency theory (depth-2 = -20%). Remaining step: VALU 6.5us is mostly
// split8, which is 256x redundant for W (t-invariant) and 4x for A (gp-waves
// share fragments). This round: W split once into 3 planar bf16 arrays in ws
// (wsplit_kernel, 6MB); h split written by the epilogue cell-owner into
// ping-pong planes (3MB; h0 in init). k-loop = pure short8 loads + MFMA:
// -25% bytes (192B vs 256B per lane/k-step), ~-4us/step VALU. Same bsplit
// function => BIT-IDENTICAL MFMA inputs => trajectory == R15 => absmax 0.0.
// ws_size guard (R4 lesson): needs 12.6MB; smaller -> <false> template =
// R15 verbatim fallback. Sync/logits/argmax/epilogue/finale: R15 verbatim.

typedef short short8 __attribute__((ext_vector_type(8)));
typedef float f32x4  __attribute__((ext_vector_type(4)));

__device__ __forceinline__ float sigf(float x){ return 1.0f/(1.0f + expf(-x)); }

__device__ __forceinline__ void bsplit(float x, short &h, short &m, short &l){
    __hip_bfloat16 bh = __float2bfloat16(x);
    float fh = __bfloat162float(bh);
    float r1 = x - fh;
    __hip_bfloat16 bm = __float2bfloat16(r1);
    float fm = __bfloat162float(bm);
    float r2 = r1 - fm;
    __hip_bfloat16 bl = __float2bfloat16(r2);
    h = __builtin_bit_cast(short, bh);
    m = __builtin_bit_cast(short, bm);
    l = __builtin_bit_cast(short, bl);
}

struct Trip { short8 h, m, l; };

__device__ __forceinline__ Trip split8(const float4 &a, const float4 &b){
    Trip t;
    const float v[8] = {a.x, a.y, a.z, a.w, b.x, b.y, b.z, b.w};
    #pragma unroll
    for (int e = 0; e < 8; ++e){
        short hh, mm, ll;
        bsplit(v[e], hh, mm, ll);
        t.h[e] = hh; t.m[e] = mm; t.l[e] = ll;
    }
    return t;
}

__device__ __forceinline__ void group_barrier(int* cnt, int target){
    __syncthreads();
    if (threadIdx.x == 0){
        __hip_atomic_fetch_add(cnt, 1, __ATOMIC_RELEASE, __HIP_MEMORY_SCOPE_AGENT);
        while (__hip_atomic_load(cnt, __ATOMIC_RELAXED, __HIP_MEMORY_SCOPE_AGENT) < target)
            __builtin_amdgcn_s_sleep(1);
        (void)__hip_atomic_load(cnt, __ATOMIC_ACQUIRE, __HIP_MEMORY_SCOPE_AGENT);
    }
    __syncthreads();
}

__global__ void init_kernel(float* lp, int* cnts){
    int i = blockIdx.x*blockDim.x + threadIdx.x;
    if (i < NGRP) cnts[i*CNT_STRIDE] = 0;
    for (int x = i; x < NLP; x += (int)(gridDim.x*blockDim.x)) lp[x] = 0.0f;
}

// one-shot: split Whh into 3 planar bf16 arrays (same bsplit -> bit-identical)
__global__ void wsplit_kernel(const float* __restrict__ Whh, float* ws){
    short* hs  = (short*)(ws + 3*BH + 1024);   // [2][3][BH]
    short* wsp = hs + 2*3*BH;                  // [3][WSZ]
    int i = blockIdx.x*blockDim.x + threadIdx.x;
    for (int x = i; x < WSZ; x += (int)(gridDim.x*blockDim.x)){
        short h, m, l; bsplit(Whh[x], h, m, l);
        wsp[x] = h; wsp[WSZ + x] = m; wsp[2*WSZ + x] = l;
    }
}

template<bool PS>
__global__ void __launch_bounds__(NTHR, 2)
decoder_rnn_kernel(const float* __restrict__ h0, const float* __restrict__ c0,
                   const float* __restrict__ tgt, const float* __restrict__ Wih,
                   const float* __restrict__ Whh, const float* __restrict__ bih,
                   const float* __restrict__ bhh, const float* __restrict__ Wout,
                   const float* __restrict__ bout, float* out, float* ws)
{
    __shared__ float red[2*32*RST];    // 33.8KB: [kh][b=32][jg=128(+4)]
    __shared__ float hn_lds[32*33];
    __shared__ int   idx_lds[32];

    float* hbuf = ws;                  // 2*BH ping-pong h (fp32, finale)
    float* cws  = ws + 2*BH;           // BH c-state
    int*   cnts = (int*)(ws + 3*BH);
    short* hs   = (short*)(ws + 3*BH + 1024);  // [buf][plane][BH] h splits
    short* wsp  = hs + 2*3*BH;                 // [plane][WSZ] W splits
    float* lp   = out;

    // XCD-aware remap (R9): same-XCD blocks share 2 jt panels.
    const int idx = blockIdx.x;
    const int jt  = ((idx & 7) << 1) | ((idx >> 7) & 1);
    const int bt  = (idx >> 3) & 15;
    const int b0  = bt << 5;
    const int j0  = jt << 5;

    const int tid  = threadIdx.x;
    const int wv   = tid >> 6;
    const int lane = tid & 63;
    const int kh   = wv & 1;           // K half (0/1)
    const int gp   = wv >> 1;          // gate owned by this wave pair (0..3)
    const int lr   = lane & 15;        // row-in-tile
    const int lk   = lane >> 4;        // k-group (0..3)
    int* cnt = cnts + bt*CNT_STRIDE;

    const int lg_bl = tid / 7, lg_v = tid % 7;

    // fragment global-address bases (element offsets; shared by both paths)
    long aoff0, aoff1, woff0, woff1;
    {
        const int kb = (kh << 8) + (lk << 3);
        aoff0 = (long)(b0 + lr)*Hn + kb;                 // A rows b0..b0+15
        aoff1 = aoff0 + (long)16*Hn;                     // A rows b0+16..31
        woff0 = (long)((gp << 9) + j0 + lr)*Hn + kb;     // W rows j0..j0+15 of gate gp
        woff1 = woff0 + (long)16*Hn;                     // W rows j0+16..31
    }

    // ---- per-block state init (R15 verbatim + h0 split planes) ----
    #pragma unroll
    for (int i = 0; i < 8; ++i){
        const int f = tid + (i << 9);
        const int r = f >> 7, c4 = f & 127;
        *(float4*)(hbuf + (long)(b0 + r)*Hn + (c4 << 2)) =
            *(const float4*)(h0 + (long)(b0 + r)*Hn + (c4 << 2));
    }
    if (tid < 256){
        const int r = tid >> 3, c4 = tid & 7;
        *(float4*)(cws + (long)(b0 + r)*Hn + j0 + (c4 << 2)) =
            *(const float4*)(c0 + (long)(b0 + r)*Hn + j0 + (c4 << 2));
    }
    if (PS){
        for (int e = tid; e < 32*Hn; e += NTHR){
            const long gi = (long)(b0 + (e >> 9))*Hn + (e & 511);
            short h, m, l; bsplit(h0[gi], h, m, l);
            hs[gi] = h; hs[BH + gi] = m; hs[2*BH + gi] = l;   // buf0 planes
        }
    }
    __syncthreads();

    for (int t = 0; t < Tn; ++t){
        const float* hprev = hbuf + (t & 1)*BH;
        float*       hnext = hbuf + ((t + 1) & 1)*BH;

        // ---- argmax -> one-hot index (R15 verbatim) ----
        if (tid < 32){
            const int  bl = tid;
            const long b  = b0 + bl;
            float best; int am = 0;
            if (t == 0){
                const float* xp = tgt + (b*Tn)*Vn;
                best = xp[0];
                #pragma unroll
                for (int v = 1; v < Vn; ++v){ float xv = xp[v]; if (xv > best){ best = xv; am = v; } }
            } else {
                const float* xp = lp + (b*Tn + (t-1))*Vn;
                best = xp[0] + bout[0];
                #pragma unroll
                for (int v = 1; v < Vn; ++v){ float xv = xp[v] + bout[v]; if (xv > best){ best = xv; am = v; } }
            }
            idx_lds[bl] = am;
        }

        f32x4 acc00 = {0.f,0.f,0.f,0.f}, acc01 = {0.f,0.f,0.f,0.f};
        f32x4 acc10 = {0.f,0.f,0.f,0.f}, acc11 = {0.f,0.f,0.f,0.f};

        if (PS){
            // ---- GEMM: pre-split planes, pure short8 loads + MFMA ----
            const short* AH = hs + (long)((t & 1)*3    )*BH;
            const short* AM = hs + (long)((t & 1)*3 + 1)*BH;
            const short* AL = hs + (long)((t & 1)*3 + 2)*BH;
            short8 rA0[4][3], rA1[4][3], rW0[4][3], rW1[4][3];  // [ring][plane]

            #define LDSLOT(p, ko) \
                rA0[p][0] = *(const short8*)(AH + aoff0 + (ko)); \
                rA0[p][1] = *(const short8*)(AM + aoff0 + (ko)); \
                rA0[p][2] = *(const short8*)(AL + aoff0 + (ko)); \
                rA1[p][0] = *(const short8*)(AH + aoff1 + (ko)); \
                rA1[p][1] = *(const short8*)(AM + aoff1 + (ko)); \
                rA1[p][2] = *(const short8*)(AL + aoff1 + (ko)); \
                rW0[p][0] = *(const short8*)(wsp +         woff0 + (ko)); \
                rW0[p][1] = *(const short8*)(wsp + WSZ   + woff0 + (ko)); \
                rW0[p][2] = *(const short8*)(wsp + 2*WSZ + woff0 + (ko)); \
                rW1[p][0] = *(const short8*)(wsp +         woff1 + (ko)); \
                rW1[p][1] = *(const short8*)(wsp + WSZ   + woff1 + (ko)); \
                rW1[p][2] = *(const short8*)(wsp + 2*WSZ + woff1 + (ko));

            LDSLOT(0, 0)
            LDSLOT(1, 32)

            #pragma unroll 4
            for (int ks = 0; ks < 8; ++ks){
                const int cb = ks & 3;
                if (ks < 6){                    // depth-2 prefetch
                    const int nb2 = (ks + 2) & 3;
                    const int ko  = (ks + 2) << 5;
                    LDSLOT(nb2, ko)
                }
                // product order h,h / h,m / m,h / h,l / m,m / l,h (R15 bitwise)
                #define MM(ai, wi) \
                    acc00 = __builtin_amdgcn_mfma_f32_16x16x32_bf16(rA0[cb][ai], rW0[cb][wi], acc00, 0,0,0); \
                    acc01 = __builtin_amdgcn_mfma_f32_16x16x32_bf16(rA0[cb][ai], rW1[cb][wi], acc01, 0,0,0); \
                    acc10 = __builtin_amdgcn_mfma_f32_16x16x32_bf16(rA1[cb][ai], rW0[cb][wi], acc10, 0,0,0); \
                    acc11 = __builtin_amdgcn_mfma_f32_16x16x32_bf16(rA1[cb][ai], rW1[cb][wi], acc11, 0,0,0);
                MM(0,0) MM(0,1) MM(1,0) MM(0,2) MM(1,1) MM(2,0)
                #undef MM
            }
            #undef LDSLOT
        } else {
            // ---- GEMM: R15 verbatim (split on the fly, ring-4 depth-2) ----
            float4 rA[4][2][2], rB[4][2][2];
            #pragma unroll
            for (int p = 0; p < 2; ++p){
                const int ko = p << 5;
                rA[p][0][0] = *(const float4*)(hprev + aoff0 + ko);
                rA[p][0][1] = *(const float4*)(hprev + aoff0 + ko + 4);
                rA[p][1][0] = *(const float4*)(hprev + aoff1 + ko);
                rA[p][1][1] = *(const float4*)(hprev + aoff1 + ko + 4);
                rB[p][0][0] = *(const float4*)(Whh + woff0 + ko);
                rB[p][0][1] = *(const float4*)(Whh + woff0 + ko + 4);
                rB[p][1][0] = *(const float4*)(Whh + woff1 + ko);
                rB[p][1][1] = *(const float4*)(Whh + woff1 + ko + 4);
            }
            #pragma unroll 4
            for (int ks = 0; ks < 8; ++ks){
                const int cb = ks & 3;
                if (ks < 6){
                    const int nb2 = (ks + 2) & 3;
                    const int ko  = (ks + 2) << 5;
                    rA[nb2][0][0] = *(const float4*)(hprev + aoff0 + ko);
                    rA[nb2][0][1] = *(const float4*)(hprev + aoff0 + ko + 4);
                    rA[nb2][1][0] = *(const float4*)(hprev + aoff1 + ko);
                    rA[nb2][1][1] = *(const float4*)(hprev + aoff1 + ko + 4);
                    rB[nb2][0][0] = *(const float4*)(Whh + woff0 + ko);
                    rB[nb2][0][1] = *(const float4*)(Whh + woff0 + ko + 4);
                    rB[nb2][1][0] = *(const float4*)(Whh + woff1 + ko);
                    rB[nb2][1][1] = *(const float4*)(Whh + woff1 + ko + 4);
                }
                const Trip A0 = split8(rA[cb][0][0], rA[cb][0][1]);
                const Trip A1 = split8(rA[cb][1][0], rA[cb][1][1]);
                const Trip W0 = split8(rB[cb][0][0], rB[cb][0][1]);
                const Trip W1 = split8(rB[cb][1][0], rB[cb][1][1]);
                #define MM(ap, wp) \
                    acc00 = __builtin_amdgcn_mfma_f32_16x16x32_bf16(A0.ap, W0.wp, acc00, 0,0,0); \
                    acc01 = __builtin_amdgcn_mfma_f32_16x16x32_bf16(A0.ap, W1.wp, acc01, 0,0,0); \
                    acc10 = __builtin_amdgcn_mfma_f32_16x16x32_bf16(A1.ap, W0.wp, acc10, 0,0,0); \
                    acc11 = __builtin_amdgcn_mfma_f32_16x16x32_bf16(A1.ap, W1.wp, acc11, 0,0,0);
                MM(h,h) MM(h,m) MM(m,h) MM(h,l) MM(m,m) MM(l,h)
                #undef MM
            }
        }

        // ---- park partials (R15 verbatim) ----
        {
            float* rp = red + kh*REDH + (gp << 5) + lr;
            const int bb = lk << 2;
            #pragma unroll
            for (int r = 0; r < 4; ++r){
                rp[(bb + r)*RST]           = acc00[r];
                rp[(bb + r)*RST + 16]      = acc01[r];
                rp[(16 + bb + r)*RST]      = acc10[r];
                rp[(16 + bb + r)*RST + 16] = acc11[r];
            }
        }
        __syncthreads();

        // ---- epilogue: 512 threads x 2 cells (R15 verbatim + split store) ----
        {
            const int b  = tid >> 4;
            const int jp = tid & 15;
            const int ix = idx_lds[b];
            short* hsn = hs + (long)(((t + 1) & 1)*3)*BH;
            float ga[4], gb_[4];
            #pragma unroll
            for (int g = 0; g < 4; ++g){
                const float2 v0 = *(const float2*)&red[       b*RST + (g << 5) + (jp << 1)];
                const float2 v1 = *(const float2*)&red[REDH + b*RST + (g << 5) + (jp << 1)];
                ga[g]  = v0.x + v1.x;
                gb_[g] = v0.y + v1.y;
            }
            #pragma unroll
            for (int u = 0; u < 2; ++u){
                const int j = (jp << 1) + u;
                float g4[4];
                #pragma unroll
                for (int g = 0; g < 4; ++g){
                    const int r = (g << 9) + j0 + j;
                    const float s = u ? gb_[g] : ga[g];
                    g4[g] = s + (Wih[r*Vn + ix] + bih[r] + bhh[r]);
                }
                const long bg = b0 + b;
                const int  jj = j0 + j;
                const float iv = sigf(g4[0]);
                const float fv = sigf(g4[1]);
                const float gv = tanhf(g4[2]);
                const float ov = sigf(g4[3]);
                const float cold = cws[bg*Hn + jj];
                const float cn2 = fv*cold + iv*gv;
                cws[bg*Hn + jj] = cn2;
                const float hn = ov * tanhf(cn2);
                hnext[bg*Hn + jj] = hn;
                hn_lds[b*33 + j] = hn;
                if (PS){
                    short sh, sm2, sl; bsplit(hn, sh, sm2, sl);
                    hsn[bg*Hn + jj]        = sh;
                    hsn[BH + bg*Hn + jj]   = sm2;
                    hsn[2*BH + bg*Hn + jj] = sl;
                }
            }
        }
        __syncthreads();

        // ---- partial logits: 16 partials x 32-j ascending, atomicAdd (R15 verbatim) ----
        if (tid < 224){
            const float* wo = Wout + lg_v*Hn + j0;
            float s = 0.0f;
            #pragma unroll
            for (int jj = 0; jj < 32; ++jj)
                s = fmaf(hn_lds[lg_bl*33 + jj], wo[jj], s);
            atomicAdd(&lp[((long)(b0 + lg_bl)*Tn + t)*Vn + lg_v], s);
        }

        group_barrier(cnt, GBLK*(t+1));
    }

    // ---- GROUP-LOCAL finale (R15 verbatim) ----
    {
        const int r0 = b0 + (jt << 1);
        #pragma unroll
        for (int rr = 0; rr < 2; ++rr){
            const long hb = (long)(r0 + rr)*Hn;
            out[NLP + hb + tid]      = hbuf[hb + tid];   // Tn even -> final h in buf 0
            out[NLP + BH + hb + tid] = cws[hb + tid];
        }
        const long row = (long)(r0 + (tid >> 8))*Tn + (tid & 255);
        float x[Vn]; float m = -INFINITY;
        #pragma unroll
        for (int v = 0; v < Vn; ++v){ x[v] = lp[row*Vn + v] + bout[v]; m = fmaxf(m, x[v]); }
        float s = 0.0f;
        #pragma unroll
        for (int v = 0; v < Vn; ++v) s += expf(x[v] - m);
        const float ls = logf(s);
        #pragma unroll
        for (int v = 0; v < Vn; ++v) lp[row*Vn + v] = x[v] - m - ls;
    }
}

extern "C" void kernel_launch(void* const* d_in, const int* in_sizes, int n_in,
                              void* d_out, int out_size, void* d_ws, size_t ws_size,
                              hipStream_t stream) {
    const float* h0   = (const float*)d_in[0];
    const float* c0   = (const float*)d_in[1];
    const float* tgt  = (const float*)d_in[2];
    const float* Wih  = (const float*)d_in[3];
    const float* Whh  = (const float*)d_in[4];
    const float* bih  = (const float*)d_in[5];
    const float* bhh  = (const float*)d_in[6];
    const float* Wout = (const float*)d_in[7];
    const float* bout = (const float*)d_in[8];
    float* out = (float*)d_out;
    float* ws  = (float*)d_ws;
    int*   cnts = (int*)(ws + 3*BH);

    init_kernel<<<256, 256, 0, stream>>>(out, cnts);

    // base 3*BH floats + 1024-float counter pad + h-split 2x3xBH shorts + W-split 3xWSZ shorts
    const size_t need = (size_t)(3*BH + 1024)*4 + (size_t)2*3*BH*2 + (size_t)3*WSZ*2;
    if (ws_size >= need){
        wsplit_kernel<<<1024, 256, 0, stream>>>(Whh, ws);
        decoder_rnn_kernel<true><<<dim3(NBLK), dim3(NTHR), 0, stream>>>(
            h0, c0, tgt, Wih, Whh, bih, bhh, Wout, bout, out, ws);
    } else {
        decoder_rnn_kernel<false><<<dim3(NBLK), dim3(NTHR), 0, stream>>>(
            h0, c0, tgt, Wih, Whh, bih, bhh, Wout, bout, out, ws);
    }
}